// Round 5
// baseline (140.202 us; speedup 1.0000x reference)
//
#include <hip/hip_runtime.h>

typedef __attribute__((ext_vector_type(8))) short short8;
typedef __attribute__((ext_vector_type(4))) float f32x4;
typedef __attribute__((ext_vector_type(16))) float f32x16;

#define B_  2
#define S_  2048
#define D_  1024
#define H_  16
#define HD_ 64
#define M_  (B_*S_)                    // 4096
#define N_  (H_*HD_)                   // 1024
#define HSZ ((size_t)B_*H_*S_*HD_)     // 4194304 elements per Q/K/V

// 0.125 * log2(e): QK^T scores land in log2 domain (exp2 = single v_exp_f32)
#define QSCALE 0.18033688011112042f

__device__ __forceinline__ unsigned short f2bf(float f) {
  unsigned int u = __float_as_uint(f);
  u += 0x7fffu + ((u >> 16) & 1u);
  return (unsigned short)(u >> 16);
}

__device__ __forceinline__ unsigned int cvt_pk_bf16(float lo, float hi) {
  unsigned int r;
  asm("v_cvt_pk_bf16_f32 %0, %1, %2" : "=v"(r) : "v"(lo), "v"(hi));
  return r;
}

__device__ __forceinline__ float exp2_fast(float x) {
  float r;
  asm("v_exp_f32 %0, %1" : "=v"(r) : "v"(x));
  return r;
}

__device__ __forceinline__ void gll16(const void* g, void* l) {
  __builtin_amdgcn_global_load_lds(
      (const __attribute__((address_space(1))) void*)g,
      (__attribute__((address_space(3))) void*)l, 16, 0, 0);
}

// ---- convert X [4096][1024] f32 -> bf16 row-major ----
__global__ void cvt_x_kernel(const float* __restrict__ x, unsigned short* __restrict__ xb) {
  int i = blockIdx.x * blockDim.x + threadIdx.x;
  float4 v = reinterpret_cast<const float4*>(x)[i];
  ushort4 o;
  o.x = f2bf(v.x); o.y = f2bf(v.y); o.z = f2bf(v.z); o.w = f2bf(v.w);
  reinterpret_cast<ushort4*>(xb)[i] = o;
}

// ---- convert W [1024][1024] f32 -> Wt bf16 with Wt[n][k] = W[k][n] ----
__global__ void cvt_w_transpose_kernel(const float* __restrict__ w0, const float* __restrict__ w1,
                                       const float* __restrict__ w2, unsigned short* __restrict__ wt) {
  __shared__ float tile[32][33];
  const float* w = blockIdx.z == 0 ? w0 : (blockIdx.z == 1 ? w1 : w2);
  unsigned short* o = wt + (size_t)blockIdx.z * D_ * N_;
  int kbase = blockIdx.y * 32, nbase = blockIdx.x * 32;
#pragma unroll
  for (int i = 0; i < 4; i++)
    tile[threadIdx.y + i*8][threadIdx.x] =
        w[(size_t)(kbase + threadIdx.y + i*8) * N_ + nbase + threadIdx.x];
  __syncthreads();
#pragma unroll
  for (int i = 0; i < 4; i++)
    o[(size_t)(nbase + threadIdx.y + i*8) * D_ + kbase + threadIdx.x] =
        f2bf(tile[threadIdx.x][threadIdx.y + i*8]);
}

// ---- QKV GEMM, m97-style. z==0: Q scaled by QSCALE. z==2: V written transposed
//      as Vt[b][h][d][s] (packed ushort4 along s). ----
__global__ __launch_bounds__(256) void qkv_gemm_kernel(const unsigned short* __restrict__ xb,
                                                       const unsigned short* __restrict__ wt,
                                                       unsigned short* __restrict__ qkv) {
  __shared__ __align__(16) unsigned short As[128 * 64];
  __shared__ __align__(16) unsigned short Bs[128 * 64];
  const unsigned short* w = wt + (size_t)blockIdx.z * D_ * N_;
  unsigned short* out = qkv + (size_t)blockIdx.z * HSZ;
  int lane = threadIdx.x & 63, wave = threadIdx.x >> 6;
  int lr = lane & 15, lk = lane >> 4;
  int mblk = blockIdx.y * 128, nblk = blockIdx.x * 128;
  int wm = (wave >> 1) * 64, wn = (wave & 1) * 64;

  int srow0 = wave * 32 + (lane >> 3);
  int scol = lane & 7;
  f32x4 acc[4][4] = {};

  for (int kk = 0; kk < D_; kk += 64) {
    __syncthreads();
#pragma unroll
    for (int it = 0; it < 4; it++) {
      int row = srow0 + it * 8;
      int ce = (scol ^ (row & 7)) * 8;
      gll16(xb + (size_t)(mblk + row) * D_ + kk + ce,
            (void*)(As + (size_t)(wave * 4 + it) * 512));
      gll16(w  + (size_t)(nblk + row) * D_ + kk + ce,
            (void*)(Bs + (size_t)(wave * 4 + it) * 512));
    }
    __syncthreads();

    short8 a[2][4], b[2][4];
#pragma unroll
    for (int i = 0; i < 4; i++) {
      int row = wm + i * 16 + lr;
      const char* rp = (const char*)As + row * 128;
#pragma unroll
      for (int ks = 0; ks < 2; ks++)
        a[ks][i] = *reinterpret_cast<const short8*>(rp + ((((ks*4 + lk) ^ (row & 7))) << 4));
    }
#pragma unroll
    for (int j = 0; j < 4; j++) {
      int row = wn + j * 16 + lr;
      const char* rp = (const char*)Bs + row * 128;
#pragma unroll
      for (int ks = 0; ks < 2; ks++)
        b[ks][j] = *reinterpret_cast<const short8*>(rp + ((((ks*4 + lk) ^ (row & 7))) << 4));
    }
#pragma unroll
    for (int ks = 0; ks < 2; ks++)
#pragma unroll
      for (int i = 0; i < 4; i++)
#pragma unroll
        for (int j = 0; j < 4; j++)
          acc[i][j] = __builtin_amdgcn_mfma_f32_16x16x32_bf16(a[ks][i], b[ks][j], acc[i][j], 0, 0, 0);
  }

  if (blockIdx.z == 2) {
#pragma unroll
    for (int i = 0; i < 4; i++) {
      int m0 = mblk + wm + i*16 + lk*4;
      int bb = m0 >> 11, s0 = m0 & (S_-1);
#pragma unroll
      for (int j = 0; j < 4; j++) {
        int n = nblk + wn + j*16 + lr;
        int h = n >> 6, d = n & (HD_-1);
        ushort4 pk;
        pk.x = f2bf(acc[i][j][0]); pk.y = f2bf(acc[i][j][1]);
        pk.z = f2bf(acc[i][j][2]); pk.w = f2bf(acc[i][j][3]);
        *reinterpret_cast<ushort4*>(out + ((size_t)(bb*H_ + h)*HD_ + d)*S_ + s0) = pk;
      }
    }
  } else {
    float qs = (blockIdx.z == 0) ? QSCALE : 1.0f;
#pragma unroll
    for (int i = 0; i < 4; i++)
#pragma unroll
      for (int j = 0; j < 4; j++)
#pragma unroll
        for (int r = 0; r < 4; r++) {
          int m = mblk + wm + i*16 + lk*4 + r;
          int n = nblk + wn + j*16 + lr;
          int bb = m >> 11, s = m & (S_-1), h = n >> 6, d = n & (HD_-1);
          out[(((size_t)bb * H_ + h) * S_ + s) * HD_ + d] = f2bf(acc[i][j][r] * qs);
        }
  }
}

// ---- Flash attention: 4 waves x 32 q-rows, KVBLK=128, swapped QK^T,
//      in-register softmax (log2 domain, defer-max), lsum via MFMA ones-trick,
//      double-buffered K/V LDS via global_load_lds, double-XOR swizzle. ----
__global__ __launch_bounds__(256) void attn_kernel(const unsigned short* __restrict__ qkv,
                                                   float* __restrict__ out) {
  // XCD-chunked swizzle: all 16 q-tiles of a bh group land on the same XCD
  int hid = blockIdx.x;
  int wrk = (hid & 7) * 64 + (hid >> 3);
  int bh = wrk >> 4, qtile = wrk & 15;

  const unsigned short* Q  = qkv +            (size_t)bh * S_ * HD_;
  const unsigned short* K  = qkv + HSZ   +    (size_t)bh * S_ * HD_;
  const unsigned short* Vt = qkv + 2*HSZ +    (size_t)bh * HD_ * S_;  // [d][s]
  int lane = threadIdx.x & 63, wave = threadIdx.x >> 6;
  int ql = lane & 31, hi = lane >> 5;
  int qbase = qtile * 128 + wave * 32;
  int tid = threadIdx.x;

  __shared__ __align__(16) unsigned short Ks[2][128 * 64];  // [kv][d], 128B rows, swizzled
  __shared__ __align__(16) unsigned short Vs[2][64 * 128];  // [d][kv], 256B rows, swizzled

// stage one 128-kv tile (K: 128x64, V^T: 64x128) starting at kv offset `kc`
#define STAGE(b, kc) do {                                                        \
    _Pragma("unroll")                                                            \
    for (int it = 0; it < 4; it++) {                                             \
      int ci = it * 256 + tid;                                                   \
      int kr = ci >> 3, kcol = ci & 7;                                           \
      gll16(K + (size_t)((kc) + kr) * HD_ +                                      \
                ((kcol ^ (kr & 7) ^ ((kr >> 3) & 7)) * 8),                       \
            (void*)(Ks[b] + (size_t)ci * 8));                                    \
      int vr = ci >> 4, vcol = ci & 15;                                          \
      gll16(Vt + (size_t)vr * S_ + (kc) +                                        \
                 ((vcol ^ (vr & 7) ^ ((vr >> 3) & 7)) * 8),                      \
            (void*)(Vs[b] + (size_t)ci * 8));                                    \
    }                                                                            \
  } while (0)

  // Q fragments (pre-scaled by QSCALE in GEMM): B-operand, col=ql, k=hi*8+e
  short8 qf[4];
#pragma unroll
  for (int ds = 0; ds < 4; ds++)
    qf[ds] = *reinterpret_cast<const short8*>(Q + (size_t)(qbase + ql) * HD_ + ds*16 + hi*8);

  // all-ones bf16 fragment for the lsum MFMA
  short8 ones;
#pragma unroll
  for (int i = 0; i < 8; i++) ones[i] = (short)0x3F80;

  f32x16 oacc[2] = {};
  f32x16 lacc = {};
  float m = -INFINITY;

  STAGE(0, 0);   // prologue

  int buf = 0;
  for (int kt = 0; kt < S_/128; kt++) {
    __syncthreads();   // stage(kt) visible (vmcnt drained before barrier)
    if (kt < S_/128 - 1) STAGE(buf^1, (kt+1)*128);

    // QK^T (swapped): sacc[kh][r] = S^T[kv = kh*32 + crow(r,hi)][q = ql]
    f32x16 sacc[4] = {};
    __builtin_amdgcn_s_setprio(1);
#pragma unroll
    for (int kh = 0; kh < 4; kh++) {
      int row = kh*32 + ql;
      const char* rp = (const char*)Ks[buf] + row * 128;
      int sw = (row & 7) ^ ((row >> 3) & 7);
#pragma unroll
      for (int ds = 0; ds < 4; ds++) {
        short8 kf = *reinterpret_cast<const short8*>(rp + (((ds*2 + hi) ^ sw) << 4));
        sacc[kh] = __builtin_amdgcn_mfma_f32_32x32x16_bf16(kf, qf[ds], sacc[kh], 0, 0, 0);
      }
    }
    __builtin_amdgcn_s_setprio(0);

    // ---- softmax (in-register, max3-friendly tree, defer-max T13) ----
    float tm[16];
#pragma unroll
    for (int r = 0; r < 16; r++)
      tm[r] = fmaxf(fmaxf(sacc[0][r], sacc[1][r]), fmaxf(sacc[2][r], sacc[3][r]));
#pragma unroll
    for (int st = 8; st > 0; st >>= 1)
#pragma unroll
      for (int r = 0; r < st; r++) tm[r] = fmaxf(tm[r], tm[r + st]);
    float mx = fmaxf(tm[0], __shfl_xor(tm[0], 32));
    if (__any(mx - m > 8.0f)) {
      float mnew = fmaxf(m, mx);
      float corr = exp2_fast(m - mnew);
      m = mnew;
      lacc[0] *= corr;
#pragma unroll
      for (int dh = 0; dh < 2; dh++)
#pragma unroll
        for (int r = 0; r < 16; r++) oacc[dh][r] *= corr;
    }
#pragma unroll
    for (int kh = 0; kh < 4; kh++)
#pragma unroll
      for (int r = 0; r < 16; r++)
        sacc[kh][r] = exp2_fast(sacc[kh][r] - m);

    // ---- P^T -> bf16 (T12) + PV + lsum-via-MFMA ----
#pragma unroll
    for (int ks = 0; ks < 8; ks++) {
      int o = (ks & 1) * 8;
      unsigned int w0 = cvt_pk_bf16(sacc[ks>>1][o+0], sacc[ks>>1][o+1]);
      unsigned int w1 = cvt_pk_bf16(sacc[ks>>1][o+2], sacc[ks>>1][o+3]);
      unsigned int w2 = cvt_pk_bf16(sacc[ks>>1][o+4], sacc[ks>>1][o+5]);
      unsigned int w3 = cvt_pk_bf16(sacc[ks>>1][o+6], sacc[ks>>1][o+7]);
      asm("v_permlane32_swap_b32 %0, %1" : "+v"(w0), "+v"(w2));
      asm("v_permlane32_swap_b32 %0, %1" : "+v"(w1), "+v"(w3));
      union { unsigned int u[4]; short8 s; } pf;
      pf.u[0] = w0; pf.u[1] = w1; pf.u[2] = w2; pf.u[3] = w3;
      __builtin_amdgcn_s_setprio(1);
      lacc = __builtin_amdgcn_mfma_f32_32x32x16_bf16(ones, pf.s, lacc, 0, 0, 0);
#pragma unroll
      for (int dh = 0; dh < 2; dh++) {
        int row = dh*32 + ql;
        int sw = (row & 7) ^ ((row >> 3) & 7);
        short8 vf = *reinterpret_cast<const short8*>(
            (const char*)Vs[buf] + row * 256 + (((ks*2 + hi) ^ sw) << 4));
        oacc[dh] = __builtin_amdgcn_mfma_f32_32x32x16_bf16(vf, pf.s, oacc[dh], 0, 0, 0);
      }
      __builtin_amdgcn_s_setprio(0);
    }
    buf ^= 1;
  }

  // epilogue: O[s][d] = O^T / lsum (lsum = lacc row 0; identical across rows)
  float inv = 1.0f / lacc[0];
  int b0 = bh >> 4, h = bh & (H_-1);
  int s = qbase + ql;
  float* orow = out + ((size_t)b0 * S_ + s) * N_ + h * HD_;
#pragma unroll
  for (int dh = 0; dh < 2; dh++)
#pragma unroll
    for (int a = 0; a < 4; a++) {
      float4 vv;
      vv.x = oacc[dh][a*4+0] * inv; vv.y = oacc[dh][a*4+1] * inv;
      vv.z = oacc[dh][a*4+2] * inv; vv.w = oacc[dh][a*4+3] * inv;
      *reinterpret_cast<float4*>(orow + dh*32 + 8*a + 4*hi) = vv;
    }
#undef STAGE
}

extern "C" void kernel_launch(void* const* d_in, const int* in_sizes, int n_in,
                              void* d_out, int out_size, void* d_ws, size_t ws_size,
                              hipStream_t stream) {
  const float* X  = (const float*)d_in[0];
  const float* Wq = (const float*)d_in[1];
  const float* Wk = (const float*)d_in[2];
  const float* Wv = (const float*)d_in[3];
  float* out = (float*)d_out;

  unsigned short* Xb  = (unsigned short*)d_ws;
  unsigned short* Wt  = Xb + (size_t)M_ * D_;
  unsigned short* QKV = Wt + (size_t)3 * D_ * N_;

  cvt_x_kernel<<<(M_*D_)/(256*4), 256, 0, stream>>>(X, Xb);
  cvt_w_transpose_kernel<<<dim3(N_/32, D_/32, 3), dim3(32, 8), 0, stream>>>(Wq, Wk, Wv, Wt);
  qkv_gemm_kernel<<<dim3(N_/128, M_/128, 3), 256, 0, stream>>>(Xb, Wt, QKV);
  attn_kernel<<<(S_/128) * (B_*H_), 256, 0, stream>>>(QKV, out);
}

// Round 6
// 129.624 us; speedup vs baseline: 1.0816x; 1.0816x over previous
//
#include <hip/hip_runtime.h>

typedef __attribute__((ext_vector_type(8))) short short8;
typedef __attribute__((ext_vector_type(4))) float f32x4;
typedef __attribute__((ext_vector_type(16))) float f32x16;

#define B_  2
#define S_  2048
#define D_  1024
#define H_  16
#define HD_ 64
#define M_  (B_*S_)                    // 4096
#define N_  (H_*HD_)                   // 1024
#define HSZ ((size_t)B_*H_*S_*HD_)     // 4194304 elements per Q/K/V
#define BHS_ (B_*H_*S_)                // 65536 q-rows total

// 0.125 * log2(e): QK^T scores land in log2 domain (exp2 = single v_exp_f32)
#define QSCALE 0.18033688011112042f

__device__ __forceinline__ unsigned short f2bf(float f) {
  unsigned int u = __float_as_uint(f);
  u += 0x7fffu + ((u >> 16) & 1u);
  return (unsigned short)(u >> 16);
}

__device__ __forceinline__ unsigned int cvt_pk_bf16(float lo, float hi) {
  unsigned int r;
  asm("v_cvt_pk_bf16_f32 %0, %1, %2" : "=v"(r) : "v"(lo), "v"(hi));
  return r;
}

__device__ __forceinline__ float exp2_fast(float x) {
  float r;
  asm("v_exp_f32 %0, %1" : "=v"(r) : "v"(x));
  return r;
}

__device__ __forceinline__ void gll16(const void* g, void* l) {
  __builtin_amdgcn_global_load_lds(
      (const __attribute__((address_space(1))) void*)g,
      (__attribute__((address_space(3))) void*)l, 16, 0, 0);
}

// ---- convert X [4096][1024] f32 -> bf16 row-major ----
__global__ void cvt_x_kernel(const float* __restrict__ x, unsigned short* __restrict__ xb) {
  int i = blockIdx.x * blockDim.x + threadIdx.x;
  float4 v = reinterpret_cast<const float4*>(x)[i];
  ushort4 o;
  o.x = f2bf(v.x); o.y = f2bf(v.y); o.z = f2bf(v.z); o.w = f2bf(v.w);
  reinterpret_cast<ushort4*>(xb)[i] = o;
}

// ---- convert W [1024][1024] f32 -> Wt bf16 with Wt[n][k] = W[k][n] ----
__global__ void cvt_w_transpose_kernel(const float* __restrict__ w0, const float* __restrict__ w1,
                                       const float* __restrict__ w2, unsigned short* __restrict__ wt) {
  __shared__ float tile[32][33];
  const float* w = blockIdx.z == 0 ? w0 : (blockIdx.z == 1 ? w1 : w2);
  unsigned short* o = wt + (size_t)blockIdx.z * D_ * N_;
  int kbase = blockIdx.y * 32, nbase = blockIdx.x * 32;
#pragma unroll
  for (int i = 0; i < 4; i++)
    tile[threadIdx.y + i*8][threadIdx.x] =
        w[(size_t)(kbase + threadIdx.y + i*8) * N_ + nbase + threadIdx.x];
  __syncthreads();
#pragma unroll
  for (int i = 0; i < 4; i++)
    o[(size_t)(nbase + threadIdx.y + i*8) * D_ + kbase + threadIdx.x] =
        f2bf(tile[threadIdx.x][threadIdx.y + i*8]);
}

// ---- QKV GEMM, m97-style. z==0: Q scaled by QSCALE. z==2: V written transposed
//      as Vt[b][h][d][s] (packed ushort4 along s). ----
__global__ __launch_bounds__(256) void qkv_gemm_kernel(const unsigned short* __restrict__ xb,
                                                       const unsigned short* __restrict__ wt,
                                                       unsigned short* __restrict__ qkv) {
  __shared__ __align__(16) unsigned short As[128 * 64];
  __shared__ __align__(16) unsigned short Bs[128 * 64];
  const unsigned short* w = wt + (size_t)blockIdx.z * D_ * N_;
  unsigned short* out = qkv + (size_t)blockIdx.z * HSZ;
  int lane = threadIdx.x & 63, wave = threadIdx.x >> 6;
  int lr = lane & 15, lk = lane >> 4;
  int mblk = blockIdx.y * 128, nblk = blockIdx.x * 128;
  int wm = (wave >> 1) * 64, wn = (wave & 1) * 64;

  int srow0 = wave * 32 + (lane >> 3);
  int scol = lane & 7;
  f32x4 acc[4][4] = {};

  for (int kk = 0; kk < D_; kk += 64) {
    __syncthreads();
#pragma unroll
    for (int it = 0; it < 4; it++) {
      int row = srow0 + it * 8;
      int ce = (scol ^ (row & 7)) * 8;
      gll16(xb + (size_t)(mblk + row) * D_ + kk + ce,
            (void*)(As + (size_t)(wave * 4 + it) * 512));
      gll16(w  + (size_t)(nblk + row) * D_ + kk + ce,
            (void*)(Bs + (size_t)(wave * 4 + it) * 512));
    }
    __syncthreads();

    short8 a[2][4], b[2][4];
#pragma unroll
    for (int i = 0; i < 4; i++) {
      int row = wm + i * 16 + lr;
      const char* rp = (const char*)As + row * 128;
#pragma unroll
      for (int ks = 0; ks < 2; ks++)
        a[ks][i] = *reinterpret_cast<const short8*>(rp + ((((ks*4 + lk) ^ (row & 7))) << 4));
    }
#pragma unroll
    for (int j = 0; j < 4; j++) {
      int row = wn + j * 16 + lr;
      const char* rp = (const char*)Bs + row * 128;
#pragma unroll
      for (int ks = 0; ks < 2; ks++)
        b[ks][j] = *reinterpret_cast<const short8*>(rp + ((((ks*4 + lk) ^ (row & 7))) << 4));
    }
#pragma unroll
    for (int ks = 0; ks < 2; ks++)
#pragma unroll
      for (int i = 0; i < 4; i++)
#pragma unroll
        for (int j = 0; j < 4; j++)
          acc[i][j] = __builtin_amdgcn_mfma_f32_16x16x32_bf16(a[ks][i], b[ks][j], acc[i][j], 0, 0, 0);
  }

  if (blockIdx.z == 2) {
#pragma unroll
    for (int i = 0; i < 4; i++) {
      int m0 = mblk + wm + i*16 + lk*4;
      int bb = m0 >> 11, s0 = m0 & (S_-1);
#pragma unroll
      for (int j = 0; j < 4; j++) {
        int n = nblk + wn + j*16 + lr;
        int h = n >> 6, d = n & (HD_-1);
        ushort4 pk;
        pk.x = f2bf(acc[i][j][0]); pk.y = f2bf(acc[i][j][1]);
        pk.z = f2bf(acc[i][j][2]); pk.w = f2bf(acc[i][j][3]);
        *reinterpret_cast<ushort4*>(out + ((size_t)(bb*H_ + h)*HD_ + d)*S_ + s0) = pk;
      }
    }
  } else {
    float qs = (blockIdx.z == 0) ? QSCALE : 1.0f;
#pragma unroll
    for (int i = 0; i < 4; i++)
#pragma unroll
      for (int j = 0; j < 4; j++)
#pragma unroll
        for (int r = 0; r < 4; r++) {
          int m = mblk + wm + i*16 + lk*4 + r;
          int n = nblk + wn + j*16 + lr;
          int bb = m >> 11, s = m & (S_-1), h = n >> 6, d = n & (HD_-1);
          out[(((size_t)bb * H_ + h) * S_ + s) * HD_ + d] = f2bf(acc[i][j][r] * qs);
        }
  }
}

// ---- Flash attention, split-KV: each block does HALF the KV range for its
//      q-tile (flash-decoding). 4 waves x 32 q-rows, KVBLK=64, swapped QK^T,
//      in-register softmax (log2 domain, defer-max), lsum via MFMA ones-trick,
//      double-buffered K/V LDS via global_load_lds. Writes unnormalized
//      O-partial + (m,l); combine_kernel merges the two halves. ----
__global__ __launch_bounds__(256, 4) void attn_kernel(const unsigned short* __restrict__ qkv,
                                                      float* __restrict__ Opart,
                                                      float* __restrict__ ML) {
  // XCD-chunked swizzle: 1024 blocks; all 32 blocks of a bh group (16 q-tiles
  // x 2 halves) land on the same XCD -> K/V L2-local.
  int hid = blockIdx.x;
  int wrk = (hid & 7) * 128 + (hid >> 3);
  int bh = wrk >> 5, qtile = (wrk >> 1) & 15, half = wrk & 1;

  const unsigned short* Q  = qkv +            (size_t)bh * S_ * HD_;
  const unsigned short* K  = qkv + HSZ   +    (size_t)bh * S_ * HD_;
  const unsigned short* Vt = qkv + 2*HSZ +    (size_t)bh * HD_ * S_;  // [d][s]
  int lane = threadIdx.x & 63, wave = threadIdx.x >> 6;
  int ql = lane & 31, hi = lane >> 5;
  int qbase = qtile * 128 + wave * 32;
  int tid = threadIdx.x;
  int kv0 = half * (S_/2);

  __shared__ __align__(16) unsigned short Ks[2][64 * 64];  // [kv][d], 128B rows
  __shared__ __align__(16) unsigned short Vs[2][64 * 64];  // [d][kv], 128B rows

// stage one 64-kv tile (K: 64x64, V^T: 64x64) at kv offset kc; double-XOR src
#define STAGE(b, kc) do {                                                        \
    _Pragma("unroll")                                                            \
    for (int it = 0; it < 2; it++) {                                             \
      int ci = it * 256 + tid;                                                   \
      int rr = ci >> 3, cc = ci & 7;                                             \
      int ce = (cc ^ (rr & 7) ^ ((rr >> 3) & 7)) * 8;                            \
      gll16(K  + (size_t)((kc) + rr) * HD_ + ce, (void*)(Ks[b] + (size_t)ci*8)); \
      gll16(Vt + (size_t)rr * S_ + (kc) + ce,    (void*)(Vs[b] + (size_t)ci*8)); \
    }                                                                            \
  } while (0)

  // Q fragments (pre-scaled by QSCALE in GEMM): B-operand, col=ql, k=hi*8+e
  short8 qf[4];
#pragma unroll
  for (int ds = 0; ds < 4; ds++)
    qf[ds] = *reinterpret_cast<const short8*>(Q + (size_t)(qbase + ql) * HD_ + ds*16 + hi*8);

  short8 ones;
#pragma unroll
  for (int i = 0; i < 8; i++) ones[i] = (short)0x3F80;

  f32x16 oacc[2] = {};
  f32x16 lacc = {};
  float m = -INFINITY;

  STAGE(0, kv0);   // prologue

  int buf = 0;
  for (int kt = 0; kt < S_/128; kt++) {   // 16 tiles of 64 kv
    __syncthreads();   // stage(kt) visible (vmcnt drained before barrier)
    if (kt < S_/128 - 1) STAGE(buf^1, kv0 + (kt+1)*64);

    // QK^T (swapped): sacc[kh][r] = S^T[kv = kh*32 + crow(r,hi)][q = ql]
    f32x16 sacc[2] = {};
    __builtin_amdgcn_s_setprio(1);
#pragma unroll
    for (int kh = 0; kh < 2; kh++) {
      int row = kh*32 + ql;
      const char* rp = (const char*)Ks[buf] + row * 128;
      int sw = (row & 7) ^ ((row >> 3) & 7);
#pragma unroll
      for (int ds = 0; ds < 4; ds++) {
        short8 kf = *reinterpret_cast<const short8*>(rp + (((ds*2 + hi) ^ sw) << 4));
        sacc[kh] = __builtin_amdgcn_mfma_f32_32x32x16_bf16(kf, qf[ds], sacc[kh], 0, 0, 0);
      }
    }
    __builtin_amdgcn_s_setprio(0);

    // ---- softmax (in-register, tree, defer-max T13) ----
    float tm[16];
#pragma unroll
    for (int r = 0; r < 16; r++) tm[r] = fmaxf(sacc[0][r], sacc[1][r]);
#pragma unroll
    for (int st = 8; st > 0; st >>= 1)
#pragma unroll
      for (int r = 0; r < st; r++) tm[r] = fmaxf(tm[r], tm[r + st]);
    float mx = fmaxf(tm[0], __shfl_xor(tm[0], 32));
    if (__any(mx - m > 8.0f)) {
      float mnew = fmaxf(m, mx);
      float corr = exp2_fast(m - mnew);
      m = mnew;
      lacc[0] *= corr;
#pragma unroll
      for (int dh = 0; dh < 2; dh++)
#pragma unroll
        for (int r = 0; r < 16; r++) oacc[dh][r] *= corr;
    }
#pragma unroll
    for (int kh = 0; kh < 2; kh++)
#pragma unroll
      for (int r = 0; r < 16; r++)
        sacc[kh][r] = exp2_fast(sacc[kh][r] - m);

    // ---- P^T -> bf16 (T12) + PV + lsum-via-MFMA ----
#pragma unroll
    for (int ks = 0; ks < 4; ks++) {
      int o = (ks & 1) * 8;
      int kh = ks >> 1;
      unsigned int w0 = cvt_pk_bf16(sacc[kh][o+0], sacc[kh][o+1]);
      unsigned int w1 = cvt_pk_bf16(sacc[kh][o+2], sacc[kh][o+3]);
      unsigned int w2 = cvt_pk_bf16(sacc[kh][o+4], sacc[kh][o+5]);
      unsigned int w3 = cvt_pk_bf16(sacc[kh][o+6], sacc[kh][o+7]);
      asm("v_permlane32_swap_b32 %0, %1" : "+v"(w0), "+v"(w2));
      asm("v_permlane32_swap_b32 %0, %1" : "+v"(w1), "+v"(w3));
      union { unsigned int u[4]; short8 s; } pf;
      pf.u[0] = w0; pf.u[1] = w1; pf.u[2] = w2; pf.u[3] = w3;
      __builtin_amdgcn_s_setprio(1);
      lacc = __builtin_amdgcn_mfma_f32_32x32x16_bf16(ones, pf.s, lacc, 0, 0, 0);
#pragma unroll
      for (int dh = 0; dh < 2; dh++) {
        int row = dh*32 + ql;
        int sw = (row & 7) ^ ((row >> 3) & 7);
        short8 vf = *reinterpret_cast<const short8*>(
            (const char*)Vs[buf] + row * 128 + (((ks*2 + hi) ^ sw) << 4));
        oacc[dh] = __builtin_amdgcn_mfma_f32_32x32x16_bf16(vf, pf.s, oacc[dh], 0, 0, 0);
      }
      __builtin_amdgcn_s_setprio(0);
    }
    buf ^= 1;
  }

  // epilogue: write unnormalized O-partial + (m, l)
  int s = qbase + ql;
  size_t prow = (size_t)half * BHS_ + (size_t)bh * S_ + s;
  float* orow = Opart + prow * HD_;
#pragma unroll
  for (int dh = 0; dh < 2; dh++)
#pragma unroll
    for (int a = 0; a < 4; a++) {
      float4 vv;
      vv.x = oacc[dh][a*4+0]; vv.y = oacc[dh][a*4+1];
      vv.z = oacc[dh][a*4+2]; vv.w = oacc[dh][a*4+3];
      *reinterpret_cast<float4*>(orow + dh*32 + 8*a + 4*hi) = vv;
    }
  if (hi == 0) {
    float2 ml; ml.x = m; ml.y = lacc[0];
    reinterpret_cast<float2*>(ML)[prow] = ml;
  }
#undef STAGE
}

// ---- combine the two KV halves: out = (O0*w0 + O1*w1) / (l0*w0 + l1*w1) ----
__global__ __launch_bounds__(256) void combine_kernel(const float* __restrict__ Opart,
                                                      const float* __restrict__ ML,
                                                      float* __restrict__ out) {
  int idx = blockIdx.x * 256 + threadIdx.x;   // over BHS_*16 float4 chunks
  int row = idx >> 4;                          // bh*S + s
  int dc = (idx & 15) * 4;
  float2 ml0 = reinterpret_cast<const float2*>(ML)[row];
  float2 ml1 = reinterpret_cast<const float2*>(ML)[BHS_ + row];
  float M = fmaxf(ml0.x, ml1.x);
  float w0 = exp2_fast(ml0.x - M), w1 = exp2_fast(ml1.x - M);
  float inv = 1.0f / (ml0.y * w0 + ml1.y * w1);
  float4 o0 = *reinterpret_cast<const float4*>(Opart + (size_t)row * HD_ + dc);
  float4 o1 = *reinterpret_cast<const float4*>(Opart + ((size_t)BHS_ + row) * HD_ + dc);
  float4 r;
  r.x = (o0.x*w0 + o1.x*w1) * inv; r.y = (o0.y*w0 + o1.y*w1) * inv;
  r.z = (o0.z*w0 + o1.z*w1) * inv; r.w = (o0.w*w0 + o1.w*w1) * inv;
  int bh = row >> 11, s = row & (S_-1);
  int b = bh >> 4, h = bh & (H_-1);
  *reinterpret_cast<float4*>(out + ((size_t)b * S_ + s) * N_ + h * HD_ + dc) = r;
}

extern "C" void kernel_launch(void* const* d_in, const int* in_sizes, int n_in,
                              void* d_out, int out_size, void* d_ws, size_t ws_size,
                              hipStream_t stream) {
  const float* X  = (const float*)d_in[0];
  const float* Wq = (const float*)d_in[1];
  const float* Wk = (const float*)d_in[2];
  const float* Wv = (const float*)d_in[3];
  float* out = (float*)d_out;

  // ws layout: Xb(8MB) | Wt(6MB) | QKV(24MB) | Opart(33.5MB f32) | ML(1MB f32)
  unsigned short* Xb  = (unsigned short*)d_ws;
  unsigned short* Wt  = Xb + (size_t)M_ * D_;
  unsigned short* QKV = Wt + (size_t)3 * D_ * N_;
  float* Opart = (float*)(QKV + 3 * HSZ);
  float* ML    = Opart + (size_t)2 * BHS_ * HD_;

  cvt_x_kernel<<<(M_*D_)/(256*4), 256, 0, stream>>>(X, Xb);
  cvt_w_transpose_kernel<<<dim3(N_/32, D_/32, 3), dim3(32, 8), 0, stream>>>(Wq, Wk, Wv, Wt);
  qkv_gemm_kernel<<<dim3(N_/128, M_/128, 3), 256, 0, stream>>>(Xb, Wt, QKV);
  attn_kernel<<<(S_/128) * (B_*H_) * 2, 256, 0, stream>>>(QKV, Opart, ML);
  combine_kernel<<<(BHS_*16)/256, 256, 0, stream>>>(Opart, ML, out);
}

// Round 7
// 122.087 us; speedup vs baseline: 1.1484x; 1.0617x over previous
//
#include <hip/hip_runtime.h>

typedef __attribute__((ext_vector_type(8))) short short8;
typedef __attribute__((ext_vector_type(4))) float f32x4;
typedef __attribute__((ext_vector_type(16))) float f32x16;

#define B_  2
#define S_  2048
#define D_  1024
#define H_  16
#define HD_ 64
#define M_  (B_*S_)                    // 4096
#define N_  (H_*HD_)                   // 1024
#define HSZ ((size_t)B_*H_*S_*HD_)     // 4194304 elements per Q/K/V
#define BHS_ (B_*H_*S_)                // 65536 q-rows total

// 0.125 * log2(e): QK^T scores land in log2 domain (exp2 = single v_exp_f32)
#define QSCALE 0.18033688011112042f

__device__ __forceinline__ unsigned short f2bf(float f) {
  unsigned int u = __float_as_uint(f);
  u += 0x7fffu + ((u >> 16) & 1u);
  return (unsigned short)(u >> 16);
}

__device__ __forceinline__ unsigned int cvt_pk_bf16(float lo, float hi) {
  unsigned int r;
  asm("v_cvt_pk_bf16_f32 %0, %1, %2" : "=v"(r) : "v"(lo), "v"(hi));
  return r;
}

__device__ __forceinline__ float exp2_fast(float x) {
  float r;
  asm("v_exp_f32 %0, %1" : "=v"(r) : "v"(x));
  return r;
}

__device__ __forceinline__ void gll16(const void* g, void* l) {
  __builtin_amdgcn_global_load_lds(
      (const __attribute__((address_space(1))) void*)g,
      (__attribute__((address_space(3))) void*)l, 16, 0, 0);
}

// ---- convert X [4096][1024] f32 -> bf16 row-major ----
__global__ void cvt_x_kernel(const float* __restrict__ x, unsigned short* __restrict__ xb) {
  int i = blockIdx.x * blockDim.x + threadIdx.x;
  float4 v = reinterpret_cast<const float4*>(x)[i];
  ushort4 o;
  o.x = f2bf(v.x); o.y = f2bf(v.y); o.z = f2bf(v.z); o.w = f2bf(v.w);
  reinterpret_cast<ushort4*>(xb)[i] = o;
}

// ---- convert W [1024][1024] f32 -> Wt bf16 with Wt[n][k] = W[k][n] ----
__global__ void cvt_w_transpose_kernel(const float* __restrict__ w0, const float* __restrict__ w1,
                                       const float* __restrict__ w2, unsigned short* __restrict__ wt) {
  __shared__ float tile[32][33];
  const float* w = blockIdx.z == 0 ? w0 : (blockIdx.z == 1 ? w1 : w2);
  unsigned short* o = wt + (size_t)blockIdx.z * D_ * N_;
  int kbase = blockIdx.y * 32, nbase = blockIdx.x * 32;
#pragma unroll
  for (int i = 0; i < 4; i++)
    tile[threadIdx.y + i*8][threadIdx.x] =
        w[(size_t)(kbase + threadIdx.y + i*8) * N_ + nbase + threadIdx.x];
  __syncthreads();
#pragma unroll
  for (int i = 0; i < 4; i++)
    o[(size_t)(nbase + threadIdx.y + i*8) * D_ + kbase + threadIdx.x] =
        f2bf(tile[threadIdx.x][threadIdx.y + i*8]);
}

// ---- QKV GEMM, m97-style. z==0: Q scaled by QSCALE. z==2: V written transposed
//      as Vt[b][h][d][s] (packed ushort4 along s). ----
__global__ __launch_bounds__(256) void qkv_gemm_kernel(const unsigned short* __restrict__ xb,
                                                       const unsigned short* __restrict__ wt,
                                                       unsigned short* __restrict__ qkv) {
  __shared__ __align__(16) unsigned short As[128 * 64];
  __shared__ __align__(16) unsigned short Bs[128 * 64];
  const unsigned short* w = wt + (size_t)blockIdx.z * D_ * N_;
  unsigned short* out = qkv + (size_t)blockIdx.z * HSZ;
  int lane = threadIdx.x & 63, wave = threadIdx.x >> 6;
  int lr = lane & 15, lk = lane >> 4;
  int mblk = blockIdx.y * 128, nblk = blockIdx.x * 128;
  int wm = (wave >> 1) * 64, wn = (wave & 1) * 64;

  int srow0 = wave * 32 + (lane >> 3);
  int scol = lane & 7;
  f32x4 acc[4][4] = {};

  for (int kk = 0; kk < D_; kk += 64) {
    __syncthreads();
#pragma unroll
    for (int it = 0; it < 4; it++) {
      int row = srow0 + it * 8;
      int ce = (scol ^ (row & 7)) * 8;
      gll16(xb + (size_t)(mblk + row) * D_ + kk + ce,
            (void*)(As + (size_t)(wave * 4 + it) * 512));
      gll16(w  + (size_t)(nblk + row) * D_ + kk + ce,
            (void*)(Bs + (size_t)(wave * 4 + it) * 512));
    }
    __syncthreads();

    short8 a[2][4], b[2][4];
#pragma unroll
    for (int i = 0; i < 4; i++) {
      int row = wm + i * 16 + lr;
      const char* rp = (const char*)As + row * 128;
#pragma unroll
      for (int ks = 0; ks < 2; ks++)
        a[ks][i] = *reinterpret_cast<const short8*>(rp + ((((ks*4 + lk) ^ (row & 7))) << 4));
    }
#pragma unroll
    for (int j = 0; j < 4; j++) {
      int row = wn + j * 16 + lr;
      const char* rp = (const char*)Bs + row * 128;
#pragma unroll
      for (int ks = 0; ks < 2; ks++)
        b[ks][j] = *reinterpret_cast<const short8*>(rp + ((((ks*4 + lk) ^ (row & 7))) << 4));
    }
#pragma unroll
    for (int ks = 0; ks < 2; ks++)
#pragma unroll
      for (int i = 0; i < 4; i++)
#pragma unroll
        for (int j = 0; j < 4; j++)
          acc[i][j] = __builtin_amdgcn_mfma_f32_16x16x32_bf16(a[ks][i], b[ks][j], acc[i][j], 0, 0, 0);
  }

  if (blockIdx.z == 2) {
#pragma unroll
    for (int i = 0; i < 4; i++) {
      int m0 = mblk + wm + i*16 + lk*4;
      int bb = m0 >> 11, s0 = m0 & (S_-1);
#pragma unroll
      for (int j = 0; j < 4; j++) {
        int n = nblk + wn + j*16 + lr;
        int h = n >> 6, d = n & (HD_-1);
        ushort4 pk;
        pk.x = f2bf(acc[i][j][0]); pk.y = f2bf(acc[i][j][1]);
        pk.z = f2bf(acc[i][j][2]); pk.w = f2bf(acc[i][j][3]);
        *reinterpret_cast<ushort4*>(out + ((size_t)(bb*H_ + h)*HD_ + d)*S_ + s0) = pk;
      }
    }
  } else {
    float qs = (blockIdx.z == 0) ? QSCALE : 1.0f;
#pragma unroll
    for (int i = 0; i < 4; i++)
#pragma unroll
      for (int j = 0; j < 4; j++)
#pragma unroll
        for (int r = 0; r < 4; r++) {
          int m = mblk + wm + i*16 + lk*4 + r;
          int n = nblk + wn + j*16 + lr;
          int bb = m >> 11, s = m & (S_-1), h = n >> 6, d = n & (HD_-1);
          out[(((size_t)bb * H_ + h) * S_ + s) * HD_ + d] = f2bf(acc[i][j][r] * qs);
        }
  }
}

// ---- Flash attention, split-KV + 64 q-rows/wave: each wave owns TWO 32-wide
//      q-subtiles; K/V fragments are read from LDS ONCE and reused for both
//      (halves LDS-read + staging traffic per FLOP). lsum for both subtiles
//      rides one MFMA accumulator via half-ones A-fragments. ----
__global__ __launch_bounds__(256, 2) void attn_kernel(const unsigned short* __restrict__ qkv,
                                                      float* __restrict__ Opart,
                                                      float* __restrict__ ML) {
  // XCD-chunked swizzle: 512 blocks; all 16 blocks of a bh group on one XCD.
  int hid = blockIdx.x;
  int wrk = (hid & 7) * 64 + (hid >> 3);
  int bh = wrk >> 4, qt2 = (wrk >> 1) & 7, half = wrk & 1;

  const unsigned short* Q  = qkv +            (size_t)bh * S_ * HD_;
  const unsigned short* K  = qkv + HSZ   +    (size_t)bh * S_ * HD_;
  const unsigned short* Vt = qkv + 2*HSZ +    (size_t)bh * HD_ * S_;  // [d][s]
  int lane = threadIdx.x & 63, wave = threadIdx.x >> 6;
  int ql = lane & 31, hi = lane >> 5;
  int qbase = qt2 * 256 + wave * 64;
  int tid = threadIdx.x;
  int kv0 = half * (S_/2);

  __shared__ __align__(16) unsigned short Ks[2][64 * 64];  // [kv][d], 128B rows
  __shared__ __align__(16) unsigned short Vs[2][64 * 64];  // [d][kv], 128B rows

#define STAGE(b, kc) do {                                                        \
    _Pragma("unroll")                                                            \
    for (int it = 0; it < 2; it++) {                                             \
      int ci = it * 256 + tid;                                                   \
      int rr = ci >> 3, cc = ci & 7;                                             \
      int ce = (cc ^ (rr & 7) ^ ((rr >> 3) & 7)) * 8;                            \
      gll16(K  + (size_t)((kc) + rr) * HD_ + ce, (void*)(Ks[b] + (size_t)ci*8)); \
      gll16(Vt + (size_t)rr * S_ + (kc) + ce,    (void*)(Vs[b] + (size_t)ci*8)); \
    }                                                                            \
  } while (0)

  // Q fragments for both subtiles (pre-scaled by QSCALE in GEMM)
  short8 qf[2][4];
#pragma unroll
  for (int qt = 0; qt < 2; qt++)
#pragma unroll
    for (int ds = 0; ds < 4; ds++)
      qf[qt][ds] = *reinterpret_cast<const short8*>(
          Q + (size_t)(qbase + qt*32 + ql) * HD_ + ds*16 + hi*8);

  // half-ones A-frags: ones0 -> rows 0-15 (lsum of qt0), ones1 -> rows 16-31
  unsigned short o0v = (ql < 16) ? 0x3F80 : 0;
  short8 ones0, ones1;
#pragma unroll
  for (int i = 0; i < 8; i++) { ones0[i] = (short)o0v; ones1[i] = (short)(o0v ^ 0x3F80); }

  f32x16 oacc[2][2] = {};   // [qt][dh]
  f32x16 lacc = {};         // regs 0-7: lsum(qt0), regs 8-15: lsum(qt1)
  float m0 = -INFINITY, m1 = -INFINITY;

  STAGE(0, kv0);   // prologue

#pragma unroll 2
  for (int kt = 0; kt < S_/128; kt++) {   // 16 tiles of 64 kv
    int buf = kt & 1;
    __syncthreads();   // stage(kt) visible (vmcnt drained before barrier)
    if (kt < S_/128 - 1) STAGE(buf^1, kv0 + (kt+1)*64);

    // K frags once into regs, reused by both q-subtiles
    short8 kf[2][4];
#pragma unroll
    for (int kh = 0; kh < 2; kh++) {
      int row = kh*32 + ql;
      const char* rp = (const char*)Ks[buf] + row * 128;
      int sw = (row & 7) ^ ((row >> 3) & 7);
#pragma unroll
      for (int ds = 0; ds < 4; ds++)
        kf[kh][ds] = *reinterpret_cast<const short8*>(rp + (((ds*2 + hi) ^ sw) << 4));
    }
    f32x16 s0[2] = {}, s1[2] = {};
    __builtin_amdgcn_s_setprio(1);
#pragma unroll
    for (int kh = 0; kh < 2; kh++)
#pragma unroll
      for (int ds = 0; ds < 4; ds++) {
        s0[kh] = __builtin_amdgcn_mfma_f32_32x32x16_bf16(kf[kh][ds], qf[0][ds], s0[kh], 0, 0, 0);
        s1[kh] = __builtin_amdgcn_mfma_f32_32x32x16_bf16(kf[kh][ds], qf[1][ds], s1[kh], 0, 0, 0);
      }
    __builtin_amdgcn_s_setprio(0);

    // ---- softmax qt0 ----
    {
      float tm[16];
#pragma unroll
      for (int r = 0; r < 16; r++) tm[r] = fmaxf(s0[0][r], s0[1][r]);
#pragma unroll
      for (int st = 8; st > 0; st >>= 1)
#pragma unroll
        for (int r = 0; r < st; r++) tm[r] = fmaxf(tm[r], tm[r + st]);
      float mx = fmaxf(tm[0], __shfl_xor(tm[0], 32));
      if (__any(mx - m0 > 8.0f)) {
        float mn = fmaxf(m0, mx);
        float c = exp2_fast(m0 - mn);
        m0 = mn;
#pragma unroll
        for (int r = 0; r < 8; r++) lacc[r] *= c;
#pragma unroll
        for (int dh = 0; dh < 2; dh++)
#pragma unroll
          for (int r = 0; r < 16; r++) oacc[0][dh][r] *= c;
      }
#pragma unroll
      for (int kh = 0; kh < 2; kh++)
#pragma unroll
        for (int r = 0; r < 16; r++) s0[kh][r] = exp2_fast(s0[kh][r] - m0);
    }
    // ---- softmax qt1 ----
    {
      float tm[16];
#pragma unroll
      for (int r = 0; r < 16; r++) tm[r] = fmaxf(s1[0][r], s1[1][r]);
#pragma unroll
      for (int st = 8; st > 0; st >>= 1)
#pragma unroll
        for (int r = 0; r < st; r++) tm[r] = fmaxf(tm[r], tm[r + st]);
      float mx = fmaxf(tm[0], __shfl_xor(tm[0], 32));
      if (__any(mx - m1 > 8.0f)) {
        float mn = fmaxf(m1, mx);
        float c = exp2_fast(m1 - mn);
        m1 = mn;
#pragma unroll
        for (int r = 8; r < 16; r++) lacc[r] *= c;
#pragma unroll
        for (int dh = 0; dh < 2; dh++)
#pragma unroll
          for (int r = 0; r < 16; r++) oacc[1][dh][r] *= c;
      }
#pragma unroll
      for (int kh = 0; kh < 2; kh++)
#pragma unroll
        for (int r = 0; r < 16; r++) s1[kh][r] = exp2_fast(s1[kh][r] - m1);
    }

    // ---- PV qt0 (V frags cached for reuse by qt1) ----
    short8 vf[4][2];
#pragma unroll
    for (int ks = 0; ks < 4; ks++) {
      int o = (ks & 1) * 8;
      int kh = ks >> 1;
      unsigned int w0 = cvt_pk_bf16(s0[kh][o+0], s0[kh][o+1]);
      unsigned int w1 = cvt_pk_bf16(s0[kh][o+2], s0[kh][o+3]);
      unsigned int w2 = cvt_pk_bf16(s0[kh][o+4], s0[kh][o+5]);
      unsigned int w3 = cvt_pk_bf16(s0[kh][o+6], s0[kh][o+7]);
      asm("v_permlane32_swap_b32 %0, %1" : "+v"(w0), "+v"(w2));
      asm("v_permlane32_swap_b32 %0, %1" : "+v"(w1), "+v"(w3));
      union { unsigned int u[4]; short8 v; } pf;
      pf.u[0] = w0; pf.u[1] = w1; pf.u[2] = w2; pf.u[3] = w3;
      __builtin_amdgcn_s_setprio(1);
      lacc = __builtin_amdgcn_mfma_f32_32x32x16_bf16(ones0, pf.v, lacc, 0, 0, 0);
#pragma unroll
      for (int dh = 0; dh < 2; dh++) {
        int row = dh*32 + ql;
        int sw = (row & 7) ^ ((row >> 3) & 7);
        vf[ks][dh] = *reinterpret_cast<const short8*>(
            (const char*)Vs[buf] + row * 128 + (((ks*2 + hi) ^ sw) << 4));
        oacc[0][dh] = __builtin_amdgcn_mfma_f32_32x32x16_bf16(vf[ks][dh], pf.v, oacc[0][dh], 0, 0, 0);
      }
      __builtin_amdgcn_s_setprio(0);
    }
    // ---- PV qt1 (reuses vf) ----
#pragma unroll
    for (int ks = 0; ks < 4; ks++) {
      int o = (ks & 1) * 8;
      int kh = ks >> 1;
      unsigned int w0 = cvt_pk_bf16(s1[kh][o+0], s1[kh][o+1]);
      unsigned int w1 = cvt_pk_bf16(s1[kh][o+2], s1[kh][o+3]);
      unsigned int w2 = cvt_pk_bf16(s1[kh][o+4], s1[kh][o+5]);
      unsigned int w3 = cvt_pk_bf16(s1[kh][o+6], s1[kh][o+7]);
      asm("v_permlane32_swap_b32 %0, %1" : "+v"(w0), "+v"(w2));
      asm("v_permlane32_swap_b32 %0, %1" : "+v"(w1), "+v"(w3));
      union { unsigned int u[4]; short8 v; } pf;
      pf.u[0] = w0; pf.u[1] = w1; pf.u[2] = w2; pf.u[3] = w3;
      __builtin_amdgcn_s_setprio(1);
      lacc = __builtin_amdgcn_mfma_f32_32x32x16_bf16(ones1, pf.v, lacc, 0, 0, 0);
#pragma unroll
      for (int dh = 0; dh < 2; dh++)
        oacc[1][dh] = __builtin_amdgcn_mfma_f32_32x32x16_bf16(vf[ks][dh], pf.v, oacc[1][dh], 0, 0, 0);
      __builtin_amdgcn_s_setprio(0);
    }
  }

  // epilogue: write unnormalized O-partials + (m, l) for both subtiles
#pragma unroll
  for (int qt = 0; qt < 2; qt++) {
    float l = lacc[qt * 8];
    int s = qbase + qt*32 + ql;
    size_t prow = (size_t)half * BHS_ + (size_t)bh * S_ + s;
    float* orow = Opart + prow * HD_;
#pragma unroll
    for (int dh = 0; dh < 2; dh++)
#pragma unroll
      for (int a = 0; a < 4; a++) {
        float4 vv;
        vv.x = oacc[qt][dh][a*4+0]; vv.y = oacc[qt][dh][a*4+1];
        vv.z = oacc[qt][dh][a*4+2]; vv.w = oacc[qt][dh][a*4+3];
        *reinterpret_cast<float4*>(orow + dh*32 + 8*a + 4*hi) = vv;
      }
    if (hi == 0) {
      float2 ml; ml.x = (qt == 0) ? m0 : m1; ml.y = l;
      reinterpret_cast<float2*>(ML)[prow] = ml;
    }
  }
#undef STAGE
}

// ---- combine the two KV halves: out = (O0*w0 + O1*w1) / (l0*w0 + l1*w1) ----
__global__ __launch_bounds__(256) void combine_kernel(const float* __restrict__ Opart,
                                                      const float* __restrict__ ML,
                                                      float* __restrict__ out) {
  int idx = blockIdx.x * 256 + threadIdx.x;   // over BHS_*16 float4 chunks
  int row = idx >> 4;                          // bh*S + s
  int dc = (idx & 15) * 4;
  float2 ml0 = reinterpret_cast<const float2*>(ML)[row];
  float2 ml1 = reinterpret_cast<const float2*>(ML)[BHS_ + row];
  float M = fmaxf(ml0.x, ml1.x);
  float w0 = exp2_fast(ml0.x - M), w1 = exp2_fast(ml1.x - M);
  float inv = 1.0f / (ml0.y * w0 + ml1.y * w1);
  float4 o0 = *reinterpret_cast<const float4*>(Opart + (size_t)row * HD_ + dc);
  float4 o1 = *reinterpret_cast<const float4*>(Opart + ((size_t)BHS_ + row) * HD_ + dc);
  float4 r;
  r.x = (o0.x*w0 + o1.x*w1) * inv; r.y = (o0.y*w0 + o1.y*w1) * inv;
  r.z = (o0.z*w0 + o1.z*w1) * inv; r.w = (o0.w*w0 + o1.w*w1) * inv;
  int bh = row >> 11, s = row & (S_-1);
  int b = bh >> 4, h = bh & (H_-1);
  *reinterpret_cast<float4*>(out + ((size_t)b * S_ + s) * N_ + h * HD_ + dc) = r;
}

extern "C" void kernel_launch(void* const* d_in, const int* in_sizes, int n_in,
                              void* d_out, int out_size, void* d_ws, size_t ws_size,
                              hipStream_t stream) {
  const float* X  = (const float*)d_in[0];
  const float* Wq = (const float*)d_in[1];
  const float* Wk = (const float*)d_in[2];
  const float* Wv = (const float*)d_in[3];
  float* out = (float*)d_out;

  // ws layout: Xb(8MB) | Wt(6MB) | QKV(24MB) | Opart(33.5MB f32) | ML(1MB f32)
  unsigned short* Xb  = (unsigned short*)d_ws;
  unsigned short* Wt  = Xb + (size_t)M_ * D_;
  unsigned short* QKV = Wt + (size_t)3 * D_ * N_;
  float* Opart = (float*)(QKV + 3 * HSZ);
  float* ML    = Opart + (size_t)2 * BHS_ * HD_;

  cvt_x_kernel<<<(M_*D_)/(256*4), 256, 0, stream>>>(X, Xb);
  cvt_w_transpose_kernel<<<dim3(N_/32, D_/32, 3), dim3(32, 8), 0, stream>>>(Wq, Wk, Wv, Wt);
  qkv_gemm_kernel<<<dim3(N_/128, M_/128, 3), 256, 0, stream>>>(Xb, Wt, QKV);
  attn_kernel<<<(S_/256) * (B_*H_) * 2, 256, 0, stream>>>(QKV, Opart, ML);
  combine_kernel<<<(BHS_*16)/256, 256, 0, stream>>>(Opart, ML, out);
}

// Round 8
// 115.601 us; speedup vs baseline: 1.2128x; 1.0561x over previous
//
#include <hip/hip_runtime.h>
#include <hip/hip_fp16.h>

typedef __attribute__((ext_vector_type(8))) short short8;
typedef __attribute__((ext_vector_type(4))) float f32x4;
typedef __attribute__((ext_vector_type(16))) float f32x16;

#define B_  2
#define S_  2048
#define D_  1024
#define H_  16
#define HD_ 64
#define M_  (B_*S_)                    // 4096
#define N_  (H_*HD_)                   // 1024
#define HSZ ((size_t)B_*H_*S_*HD_)     // 4194304 elements per Q/K/V
#define BHS_ (B_*H_*S_)                // 65536 q-rows total

// 0.125 * log2(e): QK^T scores land in log2 domain (exp2 = single v_exp_f32)
#define QSCALE 0.18033688011112042f

__device__ __forceinline__ unsigned short f2bf(float f) {
  unsigned int u = __float_as_uint(f);
  u += 0x7fffu + ((u >> 16) & 1u);
  return (unsigned short)(u >> 16);
}

__device__ __forceinline__ unsigned int cvt_pk_bf16(float lo, float hi) {
  unsigned int r;
  asm("v_cvt_pk_bf16_f32 %0, %1, %2" : "=v"(r) : "v"(lo), "v"(hi));
  return r;
}

__device__ __forceinline__ float exp2_fast(float x) {
  float r;
  asm("v_exp_f32 %0, %1" : "=v"(r) : "v"(x));
  return r;
}

__device__ __forceinline__ void gll16(const void* g, void* l) {
  __builtin_amdgcn_global_load_lds(
      (const __attribute__((address_space(1))) void*)g,
      (__attribute__((address_space(3))) void*)l, 16, 0, 0);
}

// ---- merged converts: blocks [0,4096) do X f32->bf16; [4096,7168) do W->Wt ----
__global__ __launch_bounds__(256) void cvt_all_kernel(const float* __restrict__ x,
                                                      const float* __restrict__ w0,
                                                      const float* __restrict__ w1,
                                                      const float* __restrict__ w2,
                                                      unsigned short* __restrict__ xb,
                                                      unsigned short* __restrict__ wt) {
  __shared__ float tile[32][33];
  int bid = blockIdx.x;
  if (bid < 4096) {
    int i = bid * 256 + threadIdx.x;
    float4 v = reinterpret_cast<const float4*>(x)[i];
    ushort4 o;
    o.x = f2bf(v.x); o.y = f2bf(v.y); o.z = f2bf(v.z); o.w = f2bf(v.w);
    reinterpret_cast<ushort4*>(xb)[i] = o;
    return;
  }
  int wid = bid - 4096;
  int z = wid >> 10, rem = wid & 1023;
  int nbase = (rem & 31) * 32, kbase = (rem >> 5) * 32;
  int tx = threadIdx.x & 31, ty = threadIdx.x >> 5;   // 32 x 8
  const float* w = z == 0 ? w0 : (z == 1 ? w1 : w2);
  unsigned short* o = wt + (size_t)z * D_ * N_;
#pragma unroll
  for (int i = 0; i < 4; i++)
    tile[ty + i*8][tx] = w[(size_t)(kbase + ty + i*8) * N_ + nbase + tx];
  __syncthreads();
#pragma unroll
  for (int i = 0; i < 4; i++)
    o[(size_t)(nbase + ty + i*8) * D_ + kbase + tx] = f2bf(tile[tx][ty + i*8]);
}

// ---- QKV GEMM, m97-style. z==0: Q scaled by QSCALE. z==2: V written transposed
//      as Vt[b][h][d][s] (packed ushort4 along s). ----
__global__ __launch_bounds__(256) void qkv_gemm_kernel(const unsigned short* __restrict__ xb,
                                                       const unsigned short* __restrict__ wt,
                                                       unsigned short* __restrict__ qkv) {
  __shared__ __align__(16) unsigned short As[128 * 64];
  __shared__ __align__(16) unsigned short Bs[128 * 64];
  const unsigned short* w = wt + (size_t)blockIdx.z * D_ * N_;
  unsigned short* out = qkv + (size_t)blockIdx.z * HSZ;
  int lane = threadIdx.x & 63, wave = threadIdx.x >> 6;
  int lr = lane & 15, lk = lane >> 4;
  int mblk = blockIdx.y * 128, nblk = blockIdx.x * 128;
  int wm = (wave >> 1) * 64, wn = (wave & 1) * 64;

  int srow0 = wave * 32 + (lane >> 3);
  int scol = lane & 7;
  f32x4 acc[4][4] = {};

  for (int kk = 0; kk < D_; kk += 64) {
    __syncthreads();
#pragma unroll
    for (int it = 0; it < 4; it++) {
      int row = srow0 + it * 8;
      int ce = (scol ^ (row & 7)) * 8;
      gll16(xb + (size_t)(mblk + row) * D_ + kk + ce,
            (void*)(As + (size_t)(wave * 4 + it) * 512));
      gll16(w  + (size_t)(nblk + row) * D_ + kk + ce,
            (void*)(Bs + (size_t)(wave * 4 + it) * 512));
    }
    __syncthreads();

    short8 a[2][4], b[2][4];
#pragma unroll
    for (int i = 0; i < 4; i++) {
      int row = wm + i * 16 + lr;
      const char* rp = (const char*)As + row * 128;
#pragma unroll
      for (int ks = 0; ks < 2; ks++)
        a[ks][i] = *reinterpret_cast<const short8*>(rp + ((((ks*4 + lk) ^ (row & 7))) << 4));
    }
#pragma unroll
    for (int j = 0; j < 4; j++) {
      int row = wn + j * 16 + lr;
      const char* rp = (const char*)Bs + row * 128;
#pragma unroll
      for (int ks = 0; ks < 2; ks++)
        b[ks][j] = *reinterpret_cast<const short8*>(rp + ((((ks*4 + lk) ^ (row & 7))) << 4));
    }
#pragma unroll
    for (int ks = 0; ks < 2; ks++)
#pragma unroll
      for (int i = 0; i < 4; i++)
#pragma unroll
        for (int j = 0; j < 4; j++)
          acc[i][j] = __builtin_amdgcn_mfma_f32_16x16x32_bf16(a[ks][i], b[ks][j], acc[i][j], 0, 0, 0);
  }

  if (blockIdx.z == 2) {
#pragma unroll
    for (int i = 0; i < 4; i++) {
      int m0 = mblk + wm + i*16 + lk*4;
      int bb = m0 >> 11, s0 = m0 & (S_-1);
#pragma unroll
      for (int j = 0; j < 4; j++) {
        int n = nblk + wn + j*16 + lr;
        int h = n >> 6, d = n & (HD_-1);
        ushort4 pk;
        pk.x = f2bf(acc[i][j][0]); pk.y = f2bf(acc[i][j][1]);
        pk.z = f2bf(acc[i][j][2]); pk.w = f2bf(acc[i][j][3]);
        *reinterpret_cast<ushort4*>(out + ((size_t)(bb*H_ + h)*HD_ + d)*S_ + s0) = pk;
      }
    }
  } else {
    float qs = (blockIdx.z == 0) ? QSCALE : 1.0f;
#pragma unroll
    for (int i = 0; i < 4; i++)
#pragma unroll
      for (int j = 0; j < 4; j++)
#pragma unroll
        for (int r = 0; r < 4; r++) {
          int m = mblk + wm + i*16 + lk*4 + r;
          int n = nblk + wn + j*16 + lr;
          int bb = m >> 11, s = m & (S_-1), h = n >> 6, d = n & (HD_-1);
          out[(((size_t)bb * H_ + h) * S_ + s) * HD_ + d] = f2bf(acc[i][j][r] * qs);
        }
  }
}

// ---- Flash attention, split-KV, 64 q-rows/wave, 4-buffer LDS with one
//      barrier per 2 KV tiles; lsum via VALU tree; f16 O-partials. ----
__global__ __launch_bounds__(256, 2) void attn_kernel(const unsigned short* __restrict__ qkv,
                                                      __half* __restrict__ Opart,
                                                      float* __restrict__ ML) {
  // XCD-chunked swizzle: 512 blocks; all 16 blocks of a bh group on one XCD.
  int hid = blockIdx.x;
  int wrk = (hid & 7) * 64 + (hid >> 3);
  int bh = wrk >> 4, qt2 = (wrk >> 1) & 7, half = wrk & 1;

  const unsigned short* Q  = qkv +            (size_t)bh * S_ * HD_;
  const unsigned short* K  = qkv + HSZ   +    (size_t)bh * S_ * HD_;
  const unsigned short* Vt = qkv + 2*HSZ +    (size_t)bh * HD_ * S_;  // [d][s]
  int lane = threadIdx.x & 63, wave = threadIdx.x >> 6;
  int ql = lane & 31, hi = lane >> 5;
  int qbase = qt2 * 256 + wave * 64;
  int tid = threadIdx.x;
  int kv0 = half * (S_/2);

  __shared__ __align__(16) unsigned short Ks[4][64 * 64];  // [kv][d], 128B rows
  __shared__ __align__(16) unsigned short Vs[4][64 * 64];  // [d][kv], 128B rows

// stage one 64-kv tile (K: 64x64, V^T: 64x64) at kv offset kc; double-XOR src
#define STAGE(b, kc) do {                                                        \
    _Pragma("unroll")                                                            \
    for (int it = 0; it < 2; it++) {                                             \
      int ci = it * 256 + tid;                                                   \
      int rr = ci >> 3, cc = ci & 7;                                             \
      int ce = (cc ^ (rr & 7) ^ ((rr >> 3) & 7)) * 8;                            \
      gll16(K  + (size_t)((kc) + rr) * HD_ + ce, (void*)(Ks[b] + (size_t)ci*8)); \
      gll16(Vt + (size_t)rr * S_ + (kc) + ce,    (void*)(Vs[b] + (size_t)ci*8)); \
    }                                                                            \
  } while (0)

  // Q fragments for both subtiles (pre-scaled by QSCALE in GEMM)
  short8 qf[2][4];
#pragma unroll
  for (int qt = 0; qt < 2; qt++)
#pragma unroll
    for (int ds = 0; ds < 4; ds++)
      qf[qt][ds] = *reinterpret_cast<const short8*>(
          Q + (size_t)(qbase + qt*32 + ql) * HD_ + ds*16 + hi*8);

  f32x16 oacc[2][2] = {};   // [qt][dh]
  float m0 = -INFINITY, m1 = -INFINITY;
  float lsum0 = 0.f, lsum1 = 0.f;

  STAGE(0, kv0);
  STAGE(1, kv0 + 64);

#pragma unroll 4
  for (int kt = 0; kt < 16; kt++) {   // 16 tiles of 64 kv
    int buf = kt & 3;
    if ((kt & 1) == 0) {
      __syncthreads();   // drains stages issued 2 tiles ago; syncs buffer reuse
      if (kt < 14) {
        STAGE((kt + 2) & 3, kv0 + (kt + 2) * 64);
        STAGE((kt + 3) & 3, kv0 + (kt + 3) * 64);
      }
    }

    // K frags once into regs, reused by both q-subtiles
    short8 kf[2][4];
#pragma unroll
    for (int kh = 0; kh < 2; kh++) {
      int row = kh*32 + ql;
      const char* rp = (const char*)Ks[buf] + row * 128;
      int sw = (row & 7) ^ ((row >> 3) & 7);
#pragma unroll
      for (int ds = 0; ds < 4; ds++)
        kf[kh][ds] = *reinterpret_cast<const short8*>(rp + (((ds*2 + hi) ^ sw) << 4));
    }
    f32x16 s0[2] = {}, s1[2] = {};
    __builtin_amdgcn_s_setprio(1);
#pragma unroll
    for (int kh = 0; kh < 2; kh++)
#pragma unroll
      for (int ds = 0; ds < 4; ds++) {
        s0[kh] = __builtin_amdgcn_mfma_f32_32x32x16_bf16(kf[kh][ds], qf[0][ds], s0[kh], 0, 0, 0);
        s1[kh] = __builtin_amdgcn_mfma_f32_32x32x16_bf16(kf[kh][ds], qf[1][ds], s1[kh], 0, 0, 0);
      }
    __builtin_amdgcn_s_setprio(0);

    // ---- softmax qt0 ----
    {
      float tm[8];
#pragma unroll
      for (int r = 0; r < 8; r++)
        tm[r] = fmaxf(fmaxf(s0[0][r], s0[0][r+8]), fmaxf(s0[1][r], s0[1][r+8]));
#pragma unroll
      for (int st = 4; st > 0; st >>= 1)
#pragma unroll
        for (int r = 0; r < st; r++) tm[r] = fmaxf(tm[r], tm[r + st]);
      float mx = fmaxf(tm[0], __shfl_xor(tm[0], 32));
      if (__any(mx - m0 > 8.0f)) {
        float mn = fmaxf(m0, mx);
        float c = exp2_fast(m0 - mn);
        m0 = mn;
        lsum0 *= c;
#pragma unroll
        for (int dh = 0; dh < 2; dh++)
#pragma unroll
          for (int r = 0; r < 16; r++) oacc[0][dh][r] *= c;
      }
#pragma unroll
      for (int kh = 0; kh < 2; kh++)
#pragma unroll
        for (int r = 0; r < 16; r++) s0[kh][r] = exp2_fast(s0[kh][r] - m0);
      float ts[8];
#pragma unroll
      for (int r = 0; r < 8; r++)
        ts[r] = (s0[0][r] + s0[0][r+8]) + (s0[1][r] + s0[1][r+8]);
#pragma unroll
      for (int st = 4; st > 0; st >>= 1)
#pragma unroll
        for (int r = 0; r < st; r++) ts[r] += ts[r + st];
      lsum0 += ts[0] + __shfl_xor(ts[0], 32);
    }
    // ---- softmax qt1 ----
    {
      float tm[8];
#pragma unroll
      for (int r = 0; r < 8; r++)
        tm[r] = fmaxf(fmaxf(s1[0][r], s1[0][r+8]), fmaxf(s1[1][r], s1[1][r+8]));
#pragma unroll
      for (int st = 4; st > 0; st >>= 1)
#pragma unroll
        for (int r = 0; r < st; r++) tm[r] = fmaxf(tm[r], tm[r + st]);
      float mx = fmaxf(tm[0], __shfl_xor(tm[0], 32));
      if (__any(mx - m1 > 8.0f)) {
        float mn = fmaxf(m1, mx);
        float c = exp2_fast(m1 - mn);
        m1 = mn;
        lsum1 *= c;
#pragma unroll
        for (int dh = 0; dh < 2; dh++)
#pragma unroll
          for (int r = 0; r < 16; r++) oacc[1][dh][r] *= c;
      }
#pragma unroll
      for (int kh = 0; kh < 2; kh++)
#pragma unroll
        for (int r = 0; r < 16; r++) s1[kh][r] = exp2_fast(s1[kh][r] - m1);
      float ts[8];
#pragma unroll
      for (int r = 0; r < 8; r++)
        ts[r] = (s1[0][r] + s1[0][r+8]) + (s1[1][r] + s1[1][r+8]);
#pragma unroll
      for (int st = 4; st > 0; st >>= 1)
#pragma unroll
        for (int r = 0; r < st; r++) ts[r] += ts[r + st];
      lsum1 += ts[0] + __shfl_xor(ts[0], 32);
    }

    // ---- PV qt0 (V frags cached for reuse by qt1) ----
    short8 vf[4][2];
#pragma unroll
    for (int ks = 0; ks < 4; ks++) {
      int o = (ks & 1) * 8;
      int kh = ks >> 1;
      unsigned int w0 = cvt_pk_bf16(s0[kh][o+0], s0[kh][o+1]);
      unsigned int w1 = cvt_pk_bf16(s0[kh][o+2], s0[kh][o+3]);
      unsigned int w2 = cvt_pk_bf16(s0[kh][o+4], s0[kh][o+5]);
      unsigned int w3 = cvt_pk_bf16(s0[kh][o+6], s0[kh][o+7]);
      asm("v_permlane32_swap_b32 %0, %1" : "+v"(w0), "+v"(w2));
      asm("v_permlane32_swap_b32 %0, %1" : "+v"(w1), "+v"(w3));
      union { unsigned int u[4]; short8 v; } pf;
      pf.u[0] = w0; pf.u[1] = w1; pf.u[2] = w2; pf.u[3] = w3;
      __builtin_amdgcn_s_setprio(1);
#pragma unroll
      for (int dh = 0; dh < 2; dh++) {
        int row = dh*32 + ql;
        int sw = (row & 7) ^ ((row >> 3) & 7);
        vf[ks][dh] = *reinterpret_cast<const short8*>(
            (const char*)Vs[buf] + row * 128 + (((ks*2 + hi) ^ sw) << 4));
        oacc[0][dh] = __builtin_amdgcn_mfma_f32_32x32x16_bf16(vf[ks][dh], pf.v, oacc[0][dh], 0, 0, 0);
      }
      __builtin_amdgcn_s_setprio(0);
    }
    // ---- PV qt1 (reuses vf) ----
#pragma unroll
    for (int ks = 0; ks < 4; ks++) {
      int o = (ks & 1) * 8;
      int kh = ks >> 1;
      unsigned int w0 = cvt_pk_bf16(s1[kh][o+0], s1[kh][o+1]);
      unsigned int w1 = cvt_pk_bf16(s1[kh][o+2], s1[kh][o+3]);
      unsigned int w2 = cvt_pk_bf16(s1[kh][o+4], s1[kh][o+5]);
      unsigned int w3 = cvt_pk_bf16(s1[kh][o+6], s1[kh][o+7]);
      asm("v_permlane32_swap_b32 %0, %1" : "+v"(w0), "+v"(w2));
      asm("v_permlane32_swap_b32 %0, %1" : "+v"(w1), "+v"(w3));
      union { unsigned int u[4]; short8 v; } pf;
      pf.u[0] = w0; pf.u[1] = w1; pf.u[2] = w2; pf.u[3] = w3;
      __builtin_amdgcn_s_setprio(1);
#pragma unroll
      for (int dh = 0; dh < 2; dh++)
        oacc[1][dh] = __builtin_amdgcn_mfma_f32_32x32x16_bf16(vf[ks][dh], pf.v, oacc[1][dh], 0, 0, 0);
      __builtin_amdgcn_s_setprio(0);
    }
  }

  // epilogue: write unnormalized f16 O-partials + (m, l) for both subtiles
#pragma unroll
  for (int qt = 0; qt < 2; qt++) {
    int s = qbase + qt*32 + ql;
    size_t prow = (size_t)half * BHS_ + (size_t)bh * S_ + s;
    __half* orow = Opart + prow * HD_;
#pragma unroll
    for (int dh = 0; dh < 2; dh++)
#pragma unroll
      for (int a = 0; a < 4; a++) {
        union { __half2 h[2]; uint2 u; } pk;
        pk.h[0] = __float22half2_rn(make_float2(oacc[qt][dh][a*4+0], oacc[qt][dh][a*4+1]));
        pk.h[1] = __float22half2_rn(make_float2(oacc[qt][dh][a*4+2], oacc[qt][dh][a*4+3]));
        *reinterpret_cast<uint2*>(orow + dh*32 + 8*a + 4*hi) = pk.u;
      }
    if (hi == 0) {
      float2 ml; ml.x = (qt == 0) ? m0 : m1; ml.y = (qt == 0) ? lsum0 : lsum1;
      reinterpret_cast<float2*>(ML)[prow] = ml;
    }
  }
#undef STAGE
}

// ---- combine the two KV halves: out = (O0*w0 + O1*w1) / (l0*w0 + l1*w1) ----
__global__ __launch_bounds__(256) void combine_kernel(const __half* __restrict__ Opart,
                                                      const float* __restrict__ ML,
                                                      float* __restrict__ out) {
  int idx = blockIdx.x * 256 + threadIdx.x;   // BHS_*8 threads, 8 d each
  int row = idx >> 3;                          // bh*S + s
  int dc = (idx & 7) * 8;
  float2 ml0 = reinterpret_cast<const float2*>(ML)[row];
  float2 ml1 = reinterpret_cast<const float2*>(ML)[BHS_ + row];
  float M = fmaxf(ml0.x, ml1.x);
  float w0 = exp2_fast(ml0.x - M), w1 = exp2_fast(ml1.x - M);
  float inv = 1.0f / (ml0.y * w0 + ml1.y * w1);
  const __half2* p0 = reinterpret_cast<const __half2*>(Opart + (size_t)row * HD_ + dc);
  const __half2* p1 = reinterpret_cast<const __half2*>(Opart + ((size_t)BHS_ + row) * HD_ + dc);
  float r[8];
#pragma unroll
  for (int i = 0; i < 4; i++) {
    float2 a = __half22float2(p0[i]);
    float2 b = __half22float2(p1[i]);
    r[2*i+0] = (a.x*w0 + b.x*w1) * inv;
    r[2*i+1] = (a.y*w0 + b.y*w1) * inv;
  }
  int bh = row >> 11, s = row & (S_-1);
  int b = bh >> 4, h = bh & (H_-1);
  float* po = out + ((size_t)b * S_ + s) * N_ + h * HD_ + dc;
  float4 v0; v0.x = r[0]; v0.y = r[1]; v0.z = r[2]; v0.w = r[3];
  float4 v1; v1.x = r[4]; v1.y = r[5]; v1.z = r[6]; v1.w = r[7];
  *reinterpret_cast<float4*>(po)     = v0;
  *reinterpret_cast<float4*>(po + 4) = v1;
}

extern "C" void kernel_launch(void* const* d_in, const int* in_sizes, int n_in,
                              void* d_out, int out_size, void* d_ws, size_t ws_size,
                              hipStream_t stream) {
  const float* X  = (const float*)d_in[0];
  const float* Wq = (const float*)d_in[1];
  const float* Wk = (const float*)d_in[2];
  const float* Wv = (const float*)d_in[3];
  float* out = (float*)d_out;

  // ws layout: Xb(8MB) | Wt(6MB) | QKV(25MB) | Opart f16(16.8MB) | ML(1MB)
  unsigned short* Xb  = (unsigned short*)d_ws;
  unsigned short* Wt  = Xb + (size_t)M_ * D_;
  unsigned short* QKV = Wt + (size_t)3 * D_ * N_;
  __half* Opart = (__half*)(QKV + 3 * HSZ);
  float* ML    = (float*)(Opart + (size_t)2 * BHS_ * HD_);

  cvt_all_kernel<<<4096 + 3072, 256, 0, stream>>>(X, Wq, Wk, Wv, Xb, Wt);
  qkv_gemm_kernel<<<dim3(N_/128, M_/128, 3), 256, 0, stream>>>(Xb, Wt, QKV);
  attn_kernel<<<(S_/256) * (B_*H_) * 2, 256, 0, stream>>>(QKV, Opart, ML);
  combine_kernel<<<(BHS_*8)/256, 256, 0, stream>>>(Opart, ML, out);
}